// Round 6
// baseline (219.014 us; speedup 1.0000x reference)
//
#include <hip/hip_runtime.h>
#include <math.h>

typedef __attribute__((ext_vector_type(8))) short bf16x8;
typedef __attribute__((ext_vector_type(4))) float f32x4;
typedef unsigned short ushort_t;

static __device__ inline unsigned short f2bf(float f) {
    union { float f; unsigned u; } v; v.f = f;
    unsigned r = v.u + 0x7fff + ((v.u >> 16) & 1);
    return (unsigned short)(r >> 16);
}

#if defined(__has_builtin)
#  if __has_builtin(__builtin_amdgcn_cvt_pk_bf16_f32)
#    define HAVE_PK_BF16 1
#  endif
#endif

static __device__ inline unsigned pk2bf(float a, float b) {
#ifdef HAVE_PK_BF16
    auto r = __builtin_amdgcn_cvt_pk_bf16_f32(a, b);
    unsigned u; __builtin_memcpy(&u, &r, 4);
    return u;
#else
    return (unsigned)f2bf(a) | ((unsigned)f2bf(b) << 16);
#endif
}

// load 8 consecutive fp32, convert to a bf16x8 MFMA fragment in-register
static __device__ inline bf16x8 ld8f32_bf16(const float* __restrict__ p) {
    const float4 v0 = *(const float4*)p;
    const float4 v1 = *(const float4*)(p + 4);
    union { unsigned u[4]; bf16x8 v; } t;
    t.u[0] = pk2bf(v0.x, v0.y); t.u[1] = pk2bf(v0.z, v0.w);
    t.u[2] = pk2bf(v1.x, v1.y); t.u[3] = pk2bf(v1.z, v1.w);
    return t.v;
}

// ---------------------------------------------------------------------------
// Q/K/V projections, fp32 inputs converted in-register (no convert pass).
// z=0: Q=row_emb@Wq^T -> bf16 rows; z=1: K=col_emb@Wk^T; z=2: V stored
// transposed Vt[bh][d][c]. 64x64 tile, 4 waves, direct-from-global frags.
// ---------------------------------------------------------------------------
__global__ __launch_bounds__(256) void gemm_qkv(const float* __restrict__ rowe,
                                                const float* __restrict__ cole,
                                                const float* __restrict__ Wq,
                                                const float* __restrict__ Wk,
                                                const float* __restrict__ Wv,
                                                ushort_t* __restrict__ Qb,
                                                ushort_t* __restrict__ Kb,
                                                ushort_t* __restrict__ Vt) {
    const int z = blockIdx.z;
    const float* A = (z == 0) ? rowe : cole;
    const float* B = (z == 0) ? Wq : (z == 1) ? Wk : Wv;

    const int t    = threadIdx.x;
    const int w    = t >> 6;
    const int lane = t & 63;
    const int quad = lane >> 4;
    const int sl   = lane & 15;
    const int m0 = blockIdx.x * 64 + (w >> 1) * 32;
    const int n0 = blockIdx.y * 64 + (w & 1) * 32;

    f32x4 acc[2][2] = {};

    for (int k0 = 0; k0 < 512; k0 += 32) {
        bf16x8 a[2], b[2];
#pragma unroll
        for (int rs = 0; rs < 2; ++rs)
            a[rs] = ld8f32_bf16(A + (size_t)(m0 + rs * 16 + sl) * 512 + k0 + quad * 8);
#pragma unroll
        for (int cs = 0; cs < 2; ++cs)
            b[cs] = ld8f32_bf16(B + (size_t)(n0 + cs * 16 + sl) * 512 + k0 + quad * 8);
#pragma unroll
        for (int rs = 0; rs < 2; ++rs)
#pragma unroll
            for (int cs = 0; cs < 2; ++cs)
                acc[rs][cs] = __builtin_amdgcn_mfma_f32_16x16x32_bf16(a[rs], b[cs], acc[rs][cs], 0, 0, 0);
    }

#pragma unroll
    for (int rs = 0; rs < 2; ++rs)
#pragma unroll
        for (int cs = 0; cs < 2; ++cs) {
            const int n = n0 + cs * 16 + sl;
            if (z == 2) {
                const int mb   = m0 + rs * 16 + quad * 4;
                const int bidx = mb >> 9, c = mb & 511;
                const int h = n >> 6, d = n & 63;
                ushort4 o;
                o.x = f2bf(acc[rs][cs][0]); o.y = f2bf(acc[rs][cs][1]);
                o.z = f2bf(acc[rs][cs][2]); o.w = f2bf(acc[rs][cs][3]);
                *(ushort4*)(Vt + (size_t)(((bidx * 8 + h) * 64 + d)) * 512 + c) = o;
            } else {
                ushort_t* C = (z == 0) ? Qb : Kb;
#pragma unroll
                for (int reg = 0; reg < 4; ++reg) {
                    const int m = m0 + rs * 16 + quad * 4 + reg;
                    C[(size_t)m * 512 + n] = f2bf(acc[rs][cs][reg]);
                }
            }
        }
}

// ---------------------------------------------------------------------------
// Final GEMM: out[M][512] = Aoutb(bf16) @ Wout(fp32, cvt in-register)^T.
// ---------------------------------------------------------------------------
__global__ __launch_bounds__(256) void gemm_out(const ushort_t* __restrict__ A,
                                                const float* __restrict__ B,
                                                float* __restrict__ C) {
    const int t    = threadIdx.x;
    const int w    = t >> 6;
    const int lane = t & 63;
    const int quad = lane >> 4;
    const int sl   = lane & 15;
    const int m0 = blockIdx.x * 64 + (w >> 1) * 32;
    const int n0 = blockIdx.y * 64 + (w & 1) * 32;

    f32x4 acc[2][2] = {};

    for (int k0 = 0; k0 < 512; k0 += 32) {
        bf16x8 a[2], b[2];
#pragma unroll
        for (int rs = 0; rs < 2; ++rs)
            a[rs] = *(const bf16x8*)(A + (size_t)(m0 + rs * 16 + sl) * 512 + k0 + quad * 8);
#pragma unroll
        for (int cs = 0; cs < 2; ++cs)
            b[cs] = ld8f32_bf16(B + (size_t)(n0 + cs * 16 + sl) * 512 + k0 + quad * 8);
#pragma unroll
        for (int rs = 0; rs < 2; ++rs)
#pragma unroll
            for (int cs = 0; cs < 2; ++cs)
                acc[rs][cs] = __builtin_amdgcn_mfma_f32_16x16x32_bf16(a[rs], b[cs], acc[rs][cs], 0, 0, 0);
    }

#pragma unroll
    for (int rs = 0; rs < 2; ++rs)
#pragma unroll
        for (int cs = 0; cs < 2; ++cs) {
            const int n = n0 + cs * 16 + sl;
#pragma unroll
            for (int reg = 0; reg < 4; ++reg) {
                const int m = m0 + rs * 16 + quad * 4 + reg;
                C[(size_t)m * 512 + n] = acc[rs][cs][reg];
            }
        }
}

// ---------------------------------------------------------------------------
// dot + mixing MLP v5: 512 threads (8 waves), 32x32 tile, grid (16,16,4).
// Phase A: wave w computes heads {2*(w&3), 2*(w&3)+1} for r-half (w>>2);
//          PACKED b32 dword writes (2 heads/dword) -> 4-way max conflicts
//          (v3 level), half the store count of v4's scalar b16 writes.
// Phase B: unchanged from v4 (8 m-tiles/wave, k-permuted hid layout).
// ---------------------------------------------------------------------------
__global__ __launch_bounds__(512) void dot_mlp_v5(const ushort_t* __restrict__ Qb,
                                                  const ushort_t* __restrict__ Kb,
                                                  const float* __restrict__ cost,
                                                  const float* __restrict__ W1,
                                                  const float* __restrict__ W2,
                                                  float* __restrict__ logits) {
    __shared__ ushort_t Xs[1024 * 18];      // 36 KB, row stride 18 shorts
    __shared__ ushort_t hidS[8 * 16 * 36];  // 9 KB, per-wave 16x36 shorts
    __shared__ ushort_t W1fs[128 * 16];     // 4 KB
    __shared__ ushort_t W2ss[8 * 128];      // 2 KB

    const int b  = blockIdx.z;
    const int r0 = blockIdx.y * 32;
    const int c0 = blockIdx.x * 32;
    const int t    = threadIdx.x;
    const int w    = t >> 6;
    const int lane = t & 63;
    const int quad = lane >> 4;
    const int sl   = lane & 15;

    const bf16x8 zf = {0, 0, 0, 0, 0, 0, 0, 0};

    // --- stage weights ---
    if (t < 128) {
        float s = 0.f;
#pragma unroll
        for (int h = 0; h < 8; ++h) {
            W1fs[t * 16 + h] = f2bf(W1[t * 16 + 2 * h]);
            s += W1[t * 16 + 2 * h + 1];
        }
        W1fs[t * 16 + 8] = f2bf(s);
#pragma unroll
        for (int k = 9; k < 16; ++k) W1fs[t * 16 + k] = 0;
    }
#pragma unroll
    for (int i = 0; i < 2; ++i) W2ss[t + i * 512] = f2bf(W2[t + i * 512]);

    // --- cost -> X slot 8 (dword col 4); zero cols 5..8 ---
#pragma unroll
    for (int i = 0; i < 2; ++i) {
        const int cell = t + i * 512;
        const int rl = cell >> 5, cl = cell & 31;
        unsigned* base = (unsigned*)(Xs + cell * 18 + 8);
        base[0] = (unsigned)f2bf(cost[((size_t)b * 512 + r0 + rl) * 512 + c0 + cl]);
        base[1] = 0; base[2] = 0; base[3] = 0; base[4] = 0;
    }

    // --- Phase A: heads h0=2*(w&3), h0+1 for r-half rs=w>>2 ---
    {
        const int hp = w & 3;         // head pair index -> dword column
        const int h0 = hp * 2;
        const int rs = w >> 2;
        bf16x8 af[2][2], bfr[2][2][2];
#pragma unroll
        for (int hh = 0; hh < 2; ++hh)
#pragma unroll
            for (int ks = 0; ks < 2; ++ks) {
                af[hh][ks] = *(const bf16x8*)(Qb +
                    ((size_t)(b * 512 + r0 + rs * 16 + sl) * 512 + (h0 + hh) * 64 + ks * 32 + quad * 8));
#pragma unroll
                for (int cs = 0; cs < 2; ++cs)
                    bfr[hh][cs][ks] = *(const bf16x8*)(Kb +
                        ((size_t)(b * 512 + c0 + cs * 16 + sl) * 512 + (h0 + hh) * 64 + ks * 32 + quad * 8));
            }
        f32x4 dacc[2][2];
#pragma unroll
        for (int hh = 0; hh < 2; ++hh)
#pragma unroll
            for (int cs = 0; cs < 2; ++cs) {
                f32x4 acc = {0.f, 0.f, 0.f, 0.f};
                acc = __builtin_amdgcn_mfma_f32_16x16x32_bf16(af[hh][0], bfr[hh][cs][0], acc, 0, 0, 0);
                acc = __builtin_amdgcn_mfma_f32_16x16x32_bf16(af[hh][1], bfr[hh][cs][1], acc, 0, 0, 0);
                dacc[hh][cs] = acc;
            }
        // packed b32 writes: dword column hp of each cell's X row
#pragma unroll
        for (int cs = 0; cs < 2; ++cs)
#pragma unroll
            for (int reg = 0; reg < 4; ++reg) {
                const int cell = (rs * 16 + quad * 4 + reg) * 32 + cs * 16 + sl;
                ((unsigned*)Xs)[cell * 9 + hp] =
                    pk2bf(dacc[0][cs][reg] * 0.125f, dacc[1][cs][reg] * 0.125f);
            }
    }

    __syncthreads();

    // --- Phase B ---
    bf16x8 bw1[8];
#pragma unroll
    for (int nt = 0; nt < 8; ++nt)
        bw1[nt] = (quad < 2) ? *(const bf16x8*)&W1fs[(nt * 16 + sl) * 16 + quad * 8] : zf;
    // W2 frags with permuted k: phys p -> j_chunk = (p>>1) | ((p&1)<<4)
    bf16x8 bw2[4];
#pragma unroll
    for (int ks = 0; ks < 4; ++ks) {
        union { ushort_t s[8]; bf16x8 v; } tu;
#pragma unroll
        for (int i = 0; i < 8; ++i) {
            const int p  = quad * 8 + i;
            const int jc = (p >> 1) | ((p & 1) << 4);
            tu.s[i] = (sl < 8) ? W2ss[sl * 128 + ks * 32 + jc] : (ushort_t)0;
        }
        bw2[ks] = tu.v;
    }

    ushort_t* hidW = hidS + w * (16 * 36);

#pragma unroll
    for (int mt = 0; mt < 8; ++mt) {
        const int gmt = w * 8 + mt;   // 0..63
        const int cb  = gmt * 16;

        bf16x8 a1 = zf;
        if (quad < 2) {
            const unsigned* xr = (const unsigned*)Xs + (size_t)(cb + sl) * 9 + quad * 4;
            union { unsigned u[4]; bf16x8 v; } tmp;
            tmp.u[0] = xr[0]; tmp.u[1] = xr[1]; tmp.u[2] = xr[2]; tmp.u[3] = xr[3];
            a1 = tmp.v;
        }

        f32x4 acc2 = {0.f, 0.f, 0.f, 0.f};
#pragma unroll
        for (int ks = 0; ks < 4; ++ks) {
            f32x4 z = {0.f, 0.f, 0.f, 0.f};
            const f32x4 h0 = __builtin_amdgcn_mfma_f32_16x16x32_bf16(a1, bw1[2 * ks],     z, 0, 0, 0);
            const f32x4 h1 = __builtin_amdgcn_mfma_f32_16x16x32_bf16(a1, bw1[2 * ks + 1], z, 0, 0, 0);
#pragma unroll
            for (int rp = 0; rp < 4; ++rp)
                ((unsigned*)hidW)[(quad * 4 + rp) * 18 + sl] =
                    pk2bf(fmaxf(h0[rp], 0.f), fmaxf(h1[rp], 0.f));
            union { uint2 u2[2]; bf16x8 v; } tu;
            const ushort_t* hp2 = hidW + sl * 36 + quad * 8;
            tu.u2[0] = *(const uint2*)hp2;
            tu.u2[1] = *(const uint2*)(hp2 + 4);
            acc2 = __builtin_amdgcn_mfma_f32_16x16x32_bf16(tu.v, bw2[ks], acc2, 0, 0, 0);
        }

        if (sl < 8) {
            const int r = r0 + (gmt >> 1);
            const int cbase = c0 + (gmt & 1) * 16 + quad * 4;
            float4 o; o.x = acc2[0]; o.y = acc2[1]; o.z = acc2[2]; o.w = acc2[3];
            *(float4*)&logits[((size_t)(b * 8 + sl) * 512 + r) * 512 + cbase] = o;
        }
    }
}

// ---------------------------------------------------------------------------
// Fused masked-softmax + PV v2. grid (32 r-tiles of 16, 32 bh), 256 threads.
// LDS 16.6 KB -> 4 blocks/CU at 1024 blocks (was 512 blocks @ 2/CU).
// ---------------------------------------------------------------------------
__global__ __launch_bounds__(256) void softmax_pv(const float* __restrict__ logits,
                                                  const int* __restrict__ mask,
                                                  const ushort_t* __restrict__ Vt,
                                                  ushort_t* __restrict__ Aout) {
    __shared__ ushort_t Ps[16 * 520];   // 16.6 KB, row stride 520 shorts

    const int t    = threadIdx.x;
    const int w    = t >> 6;
    const int lane = t & 63;
    const int quad = lane >> 4;
    const int sl   = lane & 15;
    const int rt = blockIdx.x;
    const int bh = blockIdx.y;
    const int r0 = rt * 16;

    // --- softmax: 4 rows per wave ---
#pragma unroll
    for (int rr = 0; rr < 4; ++rr) {
        const int row = w * 4 + rr;
        const float* lp = logits + ((size_t)bh * 512 + r0 + row) * 512;
        const int*   mp = mask   + ((size_t)bh * 512 + r0 + row) * 512;

        float v[8]; int m[8]; int allm = 1;
#pragma unroll
        for (int i = 0; i < 8; ++i) {
            v[i] = lp[lane + i * 64];
            m[i] = mp[lane + i * 64];
            allm &= (m[i] != 0);
        }
        const bool all_masked = (__all(allm) != 0);

        float mx = -__builtin_inff();
#pragma unroll
        for (int i = 0; i < 8; ++i) {
            const bool keep = all_masked || (m[i] == 0);
            if (keep) mx = fmaxf(mx, v[i]);
        }
#pragma unroll
        for (int s = 32; s > 0; s >>= 1) mx = fmaxf(mx, __shfl_xor(mx, s, 64));

        float e[8]; float sum = 0.f;
#pragma unroll
        for (int i = 0; i < 8; ++i) {
            const bool keep = all_masked || (m[i] == 0);
            e[i] = keep ? __expf(v[i] - mx) : 0.f;
            sum += e[i];
        }
#pragma unroll
        for (int s = 32; s > 0; s >>= 1) sum += __shfl_xor(sum, s, 64);

        const float inv = 1.f / sum;
#pragma unroll
        for (int i = 0; i < 8; ++i)
            Ps[row * 520 + lane + i * 64] = f2bf(e[i] * inv);
    }

    __syncthreads();

    // --- PV: wave w covers n = w*16..+15, all 16 rows ---
    const int n0w = w * 16;
    const ushort_t* vb = Vt + (size_t)bh * 64 * 512;

    f32x4 acc = {0.f, 0.f, 0.f, 0.f};
    for (int ks = 0; ks < 16; ++ks) {
        union { uint2 u2[2]; bf16x8 v; } ta;
        const ushort_t* pp = Ps + (size_t)sl * 520 + ks * 32 + quad * 8;
        ta.u2[0] = *(const uint2*)pp;
        ta.u2[1] = *(const uint2*)(pp + 4);
        const bf16x8 bv = *(const bf16x8*)(vb + (size_t)(n0w + sl) * 512 + ks * 32 + quad * 8);
        acc = __builtin_amdgcn_mfma_f32_16x16x32_bf16(ta.v, bv, acc, 0, 0, 0);
    }

    const int bidx = bh >> 3, h = bh & 7;
    ushort_t* Cb = Aout + (size_t)bidx * 512 * 512 + h * 64;
    const int n = n0w + sl;
#pragma unroll
    for (int reg = 0; reg < 4; ++reg) {
        const int m = r0 + quad * 4 + reg;
        Cb[(size_t)m * 512 + n] = f2bf(acc[reg]);
    }
}

// ---------------------------------------------------------------------------
extern "C" void kernel_launch(void* const* d_in, const int* in_sizes, int n_in,
                              void* d_out, int out_size, void* d_ws, size_t ws_size,
                              hipStream_t stream) {
    const float* row_emb = (const float*)d_in[0];
    const float* col_emb = (const float*)d_in[1];
    const float* cost    = (const float*)d_in[2];
    const int*   mask    = (const int*)d_in[3];
    const float* Wq      = (const float*)d_in[4];
    const float* Wk      = (const float*)d_in[5];
    const float* Wv      = (const float*)d_in[6];
    const float* Wmix1   = (const float*)d_in[7];
    const float* Wmix2   = (const float*)d_in[8];
    const float* Wout    = (const float*)d_in[9];
    float* out = (float*)d_out;

    char* ws = (char*)d_ws;
    const size_t MB = (size_t)1 << 20;
    ushort_t* Qb    = (ushort_t*)(ws);            // bf16 [b*512+r][512]  2 MB
    ushort_t* Kb    = (ushort_t*)(ws + 2 * MB);   // bf16 [b*512+c][512]  2 MB
    ushort_t* Vt    = (ushort_t*)(ws + 4 * MB);   // bf16 [bh][d][c]      2 MB
    ushort_t* Aoutb = (ushort_t*)(ws + 6 * MB);   // bf16 [b*512+r][512]  2 MB
    float* logitsBuf = (float*)(ws + 8 * MB);     // fp32 [bh][r][c]      33.6 MB

    gemm_qkv<<<dim3(32, 8, 3), 256, 0, stream>>>(row_emb, col_emb, Wq, Wk, Wv, Qb, Kb, Vt);

    dot_mlp_v5<<<dim3(16, 16, 4), 512, 0, stream>>>(Qb, Kb, cost, Wmix1, Wmix2, logitsBuf);

    softmax_pv<<<dim3(32, 32), 256, 0, stream>>>(logitsBuf, mask, Vt, Aoutb);

    gemm_out<<<dim3(32, 8), 256, 0, stream>>>(Aoutb, Wout, out);
}

// Round 7
// 190.614 us; speedup vs baseline: 1.1490x; 1.1490x over previous
//
#include <hip/hip_runtime.h>
#include <math.h>

typedef __attribute__((ext_vector_type(8))) short bf16x8;
typedef __attribute__((ext_vector_type(4))) float f32x4;
typedef unsigned short ushort_t;

static __device__ inline unsigned short f2bf(float f) {
    union { float f; unsigned u; } v; v.f = f;
    unsigned r = v.u + 0x7fff + ((v.u >> 16) & 1);
    return (unsigned short)(r >> 16);
}

#if defined(__has_builtin)
#  if __has_builtin(__builtin_amdgcn_cvt_pk_bf16_f32)
#    define HAVE_PK_BF16 1
#  endif
#endif

static __device__ inline unsigned pk2bf(float a, float b) {
#ifdef HAVE_PK_BF16
    auto r = __builtin_amdgcn_cvt_pk_bf16_f32(a, b);
    unsigned u; __builtin_memcpy(&u, &r, 4);
    return u;
#else
    return (unsigned)f2bf(a) | ((unsigned)f2bf(b) << 16);
#endif
}

// ---------------------------------------------------------------------------
// fp32 -> bf16 pre-convert (row_emb, col_emb, Wq, Wk, Wv, Wout) -> ws bf16.
// Streaming kernel: keeps cvt off the GEMM critical path (R6 lesson).
// ---------------------------------------------------------------------------
__global__ __launch_bounds__(256) void convert_all(const float* __restrict__ a0,
                                                   const float* __restrict__ a1,
                                                   const float* __restrict__ a2,
                                                   const float* __restrict__ a3,
                                                   const float* __restrict__ a4,
                                                   const float* __restrict__ a5,
                                                   ushort_t* __restrict__ dst) {
    const size_t e = ((size_t)blockIdx.x * 256 + threadIdx.x) * 4;
    const float* src; size_t off;
    if      (e < 1048576) { src = a0; off = 0; }
    else if (e < 2097152) { src = a1; off = 1048576; }
    else if (e < 2359296) { src = a2; off = 2097152; }
    else if (e < 2621440) { src = a3; off = 2359296; }
    else if (e < 2883584) { src = a4; off = 2621440; }
    else                  { src = a5; off = 2883584; }
    const float4 v = *(const float4*)(src + (e - off));
    uint2 o; o.x = pk2bf(v.x, v.y); o.y = pk2bf(v.z, v.w);
    *(uint2*)(dst + e) = o;
}

// ---------------------------------------------------------------------------
// Q/K/V projections (bf16 in, software-prefetch pipeline).
// z=0: Q=rowb@Wq^T -> bf16 rows; z=1: K=colb@Wk^T; z=2: V -> Vt[bh][d][c].
// Register double-buffer: loads for k-step i+1 issued before MFMAs of step i.
// ---------------------------------------------------------------------------
__global__ __launch_bounds__(256) void gemm_qkv(const ushort_t* __restrict__ rowb,
                                                const ushort_t* __restrict__ colb,
                                                const ushort_t* __restrict__ Wqb,
                                                const ushort_t* __restrict__ Wkb,
                                                const ushort_t* __restrict__ Wvb,
                                                ushort_t* __restrict__ Qb,
                                                ushort_t* __restrict__ Kb,
                                                ushort_t* __restrict__ Vt) {
    const int z = blockIdx.z;
    const ushort_t* A = (z == 0) ? rowb : colb;
    const ushort_t* B = (z == 0) ? Wqb : (z == 1) ? Wkb : Wvb;

    const int t    = threadIdx.x;
    const int w    = t >> 6;
    const int lane = t & 63;
    const int quad = lane >> 4;
    const int sl   = lane & 15;
    const int m0 = blockIdx.x * 64 + (w >> 1) * 32;
    const int n0 = blockIdx.y * 64 + (w & 1) * 32;

    const ushort_t* ap0 = A + (size_t)(m0 + sl) * 512 + quad * 8;
    const ushort_t* ap1 = A + (size_t)(m0 + 16 + sl) * 512 + quad * 8;
    const ushort_t* bp0 = B + (size_t)(n0 + sl) * 512 + quad * 8;
    const ushort_t* bp1 = B + (size_t)(n0 + 16 + sl) * 512 + quad * 8;

    f32x4 acc[2][2] = {};

    bf16x8 a0 = *(const bf16x8*)ap0;
    bf16x8 a1 = *(const bf16x8*)ap1;
    bf16x8 b0 = *(const bf16x8*)bp0;
    bf16x8 b1 = *(const bf16x8*)bp1;

    for (int ks = 0; ks < 16; ++ks) {
        bf16x8 na0, na1, nb0, nb1;
        if (ks < 15) {
            const int k0 = (ks + 1) * 32;
            na0 = *(const bf16x8*)(ap0 + k0);
            na1 = *(const bf16x8*)(ap1 + k0);
            nb0 = *(const bf16x8*)(bp0 + k0);
            nb1 = *(const bf16x8*)(bp1 + k0);
        }
        acc[0][0] = __builtin_amdgcn_mfma_f32_16x16x32_bf16(a0, b0, acc[0][0], 0, 0, 0);
        acc[0][1] = __builtin_amdgcn_mfma_f32_16x16x32_bf16(a0, b1, acc[0][1], 0, 0, 0);
        acc[1][0] = __builtin_amdgcn_mfma_f32_16x16x32_bf16(a1, b0, acc[1][0], 0, 0, 0);
        acc[1][1] = __builtin_amdgcn_mfma_f32_16x16x32_bf16(a1, b1, acc[1][1], 0, 0, 0);
        a0 = na0; a1 = na1; b0 = nb0; b1 = nb1;
    }

#pragma unroll
    for (int rs = 0; rs < 2; ++rs)
#pragma unroll
        for (int cs = 0; cs < 2; ++cs) {
            const int n = n0 + cs * 16 + sl;
            if (z == 2) {
                const int mb   = m0 + rs * 16 + quad * 4;
                const int bidx = mb >> 9, c = mb & 511;
                const int h = n >> 6, d = n & 63;
                ushort4 o;
                o.x = f2bf(acc[rs][cs][0]); o.y = f2bf(acc[rs][cs][1]);
                o.z = f2bf(acc[rs][cs][2]); o.w = f2bf(acc[rs][cs][3]);
                *(ushort4*)(Vt + (size_t)(((bidx * 8 + h) * 64 + d)) * 512 + c) = o;
            } else {
                ushort_t* C = (z == 0) ? Qb : Kb;
#pragma unroll
                for (int reg = 0; reg < 4; ++reg) {
                    const int m = m0 + rs * 16 + quad * 4 + reg;
                    C[(size_t)m * 512 + n] = f2bf(acc[rs][cs][reg]);
                }
            }
        }
}

// ---------------------------------------------------------------------------
// Final GEMM: out[M][512] = Aoutb(bf16) @ Woutb(bf16)^T, fp32 out. Prefetched.
// ---------------------------------------------------------------------------
__global__ __launch_bounds__(256) void gemm_out(const ushort_t* __restrict__ A,
                                                const ushort_t* __restrict__ B,
                                                float* __restrict__ C) {
    const int t    = threadIdx.x;
    const int w    = t >> 6;
    const int lane = t & 63;
    const int quad = lane >> 4;
    const int sl   = lane & 15;
    const int m0 = blockIdx.x * 64 + (w >> 1) * 32;
    const int n0 = blockIdx.y * 64 + (w & 1) * 32;

    const ushort_t* ap0 = A + (size_t)(m0 + sl) * 512 + quad * 8;
    const ushort_t* ap1 = A + (size_t)(m0 + 16 + sl) * 512 + quad * 8;
    const ushort_t* bp0 = B + (size_t)(n0 + sl) * 512 + quad * 8;
    const ushort_t* bp1 = B + (size_t)(n0 + 16 + sl) * 512 + quad * 8;

    f32x4 acc[2][2] = {};

    bf16x8 a0 = *(const bf16x8*)ap0;
    bf16x8 a1 = *(const bf16x8*)ap1;
    bf16x8 b0 = *(const bf16x8*)bp0;
    bf16x8 b1 = *(const bf16x8*)bp1;

    for (int ks = 0; ks < 16; ++ks) {
        bf16x8 na0, na1, nb0, nb1;
        if (ks < 15) {
            const int k0 = (ks + 1) * 32;
            na0 = *(const bf16x8*)(ap0 + k0);
            na1 = *(const bf16x8*)(ap1 + k0);
            nb0 = *(const bf16x8*)(bp0 + k0);
            nb1 = *(const bf16x8*)(bp1 + k0);
        }
        acc[0][0] = __builtin_amdgcn_mfma_f32_16x16x32_bf16(a0, b0, acc[0][0], 0, 0, 0);
        acc[0][1] = __builtin_amdgcn_mfma_f32_16x16x32_bf16(a0, b1, acc[0][1], 0, 0, 0);
        acc[1][0] = __builtin_amdgcn_mfma_f32_16x16x32_bf16(a1, b0, acc[1][0], 0, 0, 0);
        acc[1][1] = __builtin_amdgcn_mfma_f32_16x16x32_bf16(a1, b1, acc[1][1], 0, 0, 0);
        a0 = na0; a1 = na1; b0 = nb0; b1 = nb1;
    }

#pragma unroll
    for (int rs = 0; rs < 2; ++rs)
#pragma unroll
        for (int cs = 0; cs < 2; ++cs) {
            const int n = n0 + cs * 16 + sl;
#pragma unroll
            for (int reg = 0; reg < 4; ++reg) {
                const int m = m0 + rs * 16 + quad * 4 + reg;
                C[(size_t)m * 512 + n] = acc[rs][cs][reg];
            }
        }
}

// ---------------------------------------------------------------------------
// dot + mixing MLP v5: 512 threads (8 waves), 32x32 tile, grid (16,16,4).
// Phase A: wave w -> heads {2*(w&3), 2*(w&3)+1}, r-half (w>>2); packed b32
// dword writes. Phase B: 8 m-tiles/wave, k-permuted hid layout.
// ---------------------------------------------------------------------------
__global__ __launch_bounds__(512) void dot_mlp_v5(const ushort_t* __restrict__ Qb,
                                                  const ushort_t* __restrict__ Kb,
                                                  const float* __restrict__ cost,
                                                  const float* __restrict__ W1,
                                                  const float* __restrict__ W2,
                                                  float* __restrict__ logits) {
    __shared__ ushort_t Xs[1024 * 18];      // 36 KB
    __shared__ ushort_t hidS[8 * 16 * 36];  // 9 KB
    __shared__ ushort_t W1fs[128 * 16];     // 4 KB
    __shared__ ushort_t W2ss[8 * 128];      // 2 KB

    const int b  = blockIdx.z;
    const int r0 = blockIdx.y * 32;
    const int c0 = blockIdx.x * 32;
    const int t    = threadIdx.x;
    const int w    = t >> 6;
    const int lane = t & 63;
    const int quad = lane >> 4;
    const int sl   = lane & 15;

    const bf16x8 zf = {0, 0, 0, 0, 0, 0, 0, 0};

    if (t < 128) {
        float s = 0.f;
#pragma unroll
        for (int h = 0; h < 8; ++h) {
            W1fs[t * 16 + h] = f2bf(W1[t * 16 + 2 * h]);
            s += W1[t * 16 + 2 * h + 1];
        }
        W1fs[t * 16 + 8] = f2bf(s);
#pragma unroll
        for (int k = 9; k < 16; ++k) W1fs[t * 16 + k] = 0;
    }
#pragma unroll
    for (int i = 0; i < 2; ++i) W2ss[t + i * 512] = f2bf(W2[t + i * 512]);

#pragma unroll
    for (int i = 0; i < 2; ++i) {
        const int cell = t + i * 512;
        const int rl = cell >> 5, cl = cell & 31;
        unsigned* base = (unsigned*)(Xs + cell * 18 + 8);
        base[0] = (unsigned)f2bf(cost[((size_t)b * 512 + r0 + rl) * 512 + c0 + cl]);
        base[1] = 0; base[2] = 0; base[3] = 0; base[4] = 0;
    }

    // --- Phase A ---
    {
        const int hp = w & 3;
        const int h0 = hp * 2;
        const int rs = w >> 2;
        bf16x8 af[2][2], bfr[2][2][2];
#pragma unroll
        for (int hh = 0; hh < 2; ++hh)
#pragma unroll
            for (int ks = 0; ks < 2; ++ks) {
                af[hh][ks] = *(const bf16x8*)(Qb +
                    ((size_t)(b * 512 + r0 + rs * 16 + sl) * 512 + (h0 + hh) * 64 + ks * 32 + quad * 8));
#pragma unroll
                for (int cs = 0; cs < 2; ++cs)
                    bfr[hh][cs][ks] = *(const bf16x8*)(Kb +
                        ((size_t)(b * 512 + c0 + cs * 16 + sl) * 512 + (h0 + hh) * 64 + ks * 32 + quad * 8));
            }
        f32x4 dacc[2][2];
#pragma unroll
        for (int hh = 0; hh < 2; ++hh)
#pragma unroll
            for (int cs = 0; cs < 2; ++cs) {
                f32x4 acc = {0.f, 0.f, 0.f, 0.f};
                acc = __builtin_amdgcn_mfma_f32_16x16x32_bf16(af[hh][0], bfr[hh][cs][0], acc, 0, 0, 0);
                acc = __builtin_amdgcn_mfma_f32_16x16x32_bf16(af[hh][1], bfr[hh][cs][1], acc, 0, 0, 0);
                dacc[hh][cs] = acc;
            }
#pragma unroll
        for (int cs = 0; cs < 2; ++cs)
#pragma unroll
            for (int reg = 0; reg < 4; ++reg) {
                const int cell = (rs * 16 + quad * 4 + reg) * 32 + cs * 16 + sl;
                ((unsigned*)Xs)[cell * 9 + hp] =
                    pk2bf(dacc[0][cs][reg] * 0.125f, dacc[1][cs][reg] * 0.125f);
            }
    }

    __syncthreads();

    // --- Phase B ---
    bf16x8 bw1[8];
#pragma unroll
    for (int nt = 0; nt < 8; ++nt)
        bw1[nt] = (quad < 2) ? *(const bf16x8*)&W1fs[(nt * 16 + sl) * 16 + quad * 8] : zf;
    bf16x8 bw2[4];
#pragma unroll
    for (int ks = 0; ks < 4; ++ks) {
        union { ushort_t s[8]; bf16x8 v; } tu;
#pragma unroll
        for (int i = 0; i < 8; ++i) {
            const int p  = quad * 8 + i;
            const int jc = (p >> 1) | ((p & 1) << 4);
            tu.s[i] = (sl < 8) ? W2ss[sl * 128 + ks * 32 + jc] : (ushort_t)0;
        }
        bw2[ks] = tu.v;
    }

    ushort_t* hidW = hidS + w * (16 * 36);

#pragma unroll
    for (int mt = 0; mt < 8; ++mt) {
        const int gmt = w * 8 + mt;
        const int cb  = gmt * 16;

        bf16x8 a1 = zf;
        if (quad < 2) {
            const unsigned* xr = (const unsigned*)Xs + (size_t)(cb + sl) * 9 + quad * 4;
            union { unsigned u[4]; bf16x8 v; } tmp;
            tmp.u[0] = xr[0]; tmp.u[1] = xr[1]; tmp.u[2] = xr[2]; tmp.u[3] = xr[3];
            a1 = tmp.v;
        }

        f32x4 acc2 = {0.f, 0.f, 0.f, 0.f};
#pragma unroll
        for (int ks = 0; ks < 4; ++ks) {
            f32x4 z = {0.f, 0.f, 0.f, 0.f};
            const f32x4 h0 = __builtin_amdgcn_mfma_f32_16x16x32_bf16(a1, bw1[2 * ks],     z, 0, 0, 0);
            const f32x4 h1 = __builtin_amdgcn_mfma_f32_16x16x32_bf16(a1, bw1[2 * ks + 1], z, 0, 0, 0);
#pragma unroll
            for (int rp = 0; rp < 4; ++rp)
                ((unsigned*)hidW)[(quad * 4 + rp) * 18 + sl] =
                    pk2bf(fmaxf(h0[rp], 0.f), fmaxf(h1[rp], 0.f));
            union { uint2 u2[2]; bf16x8 v; } tu;
            const ushort_t* hp2 = hidW + sl * 36 + quad * 8;
            tu.u2[0] = *(const uint2*)hp2;
            tu.u2[1] = *(const uint2*)(hp2 + 4);
            acc2 = __builtin_amdgcn_mfma_f32_16x16x32_bf16(tu.v, bw2[ks], acc2, 0, 0, 0);
        }

        if (sl < 8) {
            const int r = r0 + (gmt >> 1);
            const int cbase = c0 + (gmt & 1) * 16 + quad * 4;
            float4 o; o.x = acc2[0]; o.y = acc2[1]; o.z = acc2[2]; o.w = acc2[3];
            *(float4*)&logits[((size_t)(b * 8 + sl) * 512 + r) * 512 + cbase] = o;
        }
    }
}

// ---------------------------------------------------------------------------
// Fused masked-softmax + PV. grid (32 r-tiles of 16, 32 bh), 256 threads.
// ---------------------------------------------------------------------------
__global__ __launch_bounds__(256) void softmax_pv(const float* __restrict__ logits,
                                                  const int* __restrict__ mask,
                                                  const ushort_t* __restrict__ Vt,
                                                  ushort_t* __restrict__ Aout) {
    __shared__ ushort_t Ps[16 * 520];   // 16.6 KB

    const int t    = threadIdx.x;
    const int w    = t >> 6;
    const int lane = t & 63;
    const int quad = lane >> 4;
    const int sl   = lane & 15;
    const int rt = blockIdx.x;
    const int bh = blockIdx.y;
    const int r0 = rt * 16;

#pragma unroll
    for (int rr = 0; rr < 4; ++rr) {
        const int row = w * 4 + rr;
        const float* lp = logits + ((size_t)bh * 512 + r0 + row) * 512;
        const int*   mp = mask   + ((size_t)bh * 512 + r0 + row) * 512;

        float v[8]; int m[8]; int allm = 1;
#pragma unroll
        for (int i = 0; i < 8; ++i) {
            v[i] = lp[lane + i * 64];
            m[i] = mp[lane + i * 64];
            allm &= (m[i] != 0);
        }
        const bool all_masked = (__all(allm) != 0);

        float mx = -__builtin_inff();
#pragma unroll
        for (int i = 0; i < 8; ++i) {
            const bool keep = all_masked || (m[i] == 0);
            if (keep) mx = fmaxf(mx, v[i]);
        }
#pragma unroll
        for (int s = 32; s > 0; s >>= 1) mx = fmaxf(mx, __shfl_xor(mx, s, 64));

        float e[8]; float sum = 0.f;
#pragma unroll
        for (int i = 0; i < 8; ++i) {
            const bool keep = all_masked || (m[i] == 0);
            e[i] = keep ? __expf(v[i] - mx) : 0.f;
            sum += e[i];
        }
#pragma unroll
        for (int s = 32; s > 0; s >>= 1) sum += __shfl_xor(sum, s, 64);

        const float inv = 1.f / sum;
#pragma unroll
        for (int i = 0; i < 8; ++i)
            Ps[row * 520 + lane + i * 64] = f2bf(e[i] * inv);
    }

    __syncthreads();

    const int n0w = w * 16;
    const ushort_t* vb = Vt + (size_t)bh * 64 * 512;

    f32x4 acc = {0.f, 0.f, 0.f, 0.f};
    for (int ks = 0; ks < 16; ++ks) {
        union { uint2 u2[2]; bf16x8 v; } ta;
        const ushort_t* pp = Ps + (size_t)sl * 520 + ks * 32 + quad * 8;
        ta.u2[0] = *(const uint2*)pp;
        ta.u2[1] = *(const uint2*)(pp + 4);
        const bf16x8 bv = *(const bf16x8*)(vb + (size_t)(n0w + sl) * 512 + ks * 32 + quad * 8);
        acc = __builtin_amdgcn_mfma_f32_16x16x32_bf16(ta.v, bv, acc, 0, 0, 0);
    }

    const int bidx = bh >> 3, h = bh & 7;
    ushort_t* Cb = Aout + (size_t)bidx * 512 * 512 + h * 64;
    const int n = n0w + sl;
#pragma unroll
    for (int reg = 0; reg < 4; ++reg) {
        const int m = r0 + quad * 4 + reg;
        Cb[(size_t)m * 512 + n] = f2bf(acc[reg]);
    }
}

// ---------------------------------------------------------------------------
extern "C" void kernel_launch(void* const* d_in, const int* in_sizes, int n_in,
                              void* d_out, int out_size, void* d_ws, size_t ws_size,
                              hipStream_t stream) {
    const float* row_emb = (const float*)d_in[0];
    const float* col_emb = (const float*)d_in[1];
    const float* cost    = (const float*)d_in[2];
    const int*   mask    = (const int*)d_in[3];
    const float* Wq      = (const float*)d_in[4];
    const float* Wk      = (const float*)d_in[5];
    const float* Wv      = (const float*)d_in[6];
    const float* Wmix1   = (const float*)d_in[7];
    const float* Wmix2   = (const float*)d_in[8];
    const float* Wout    = (const float*)d_in[9];
    float* out = (float*)d_out;

    char* ws = (char*)d_ws;
    const size_t MB = (size_t)1 << 20;
    ushort_t* convDst = (ushort_t*)ws;                       // 6 MB bf16 region:
    ushort_t* rowb  = (ushort_t*)(ws);                       //   [0,2MB)
    ushort_t* colb  = (ushort_t*)(ws + 2 * MB);              //   [2,4MB)
    ushort_t* Wqb   = (ushort_t*)(ws + 4 * MB);              //   [4,4.5MB)
    ushort_t* Wkb   = (ushort_t*)(ws + 4 * MB + 512 * 1024); //   [4.5,5MB)
    ushort_t* Wvb   = (ushort_t*)(ws + 5 * MB);              //   [5,5.5MB)
    ushort_t* Woutb = (ushort_t*)(ws + 5 * MB + 512 * 1024); //   [5.5,6MB)
    ushort_t* Qb    = (ushort_t*)(ws + 6 * MB);              // bf16 [b*512+r][512]
    ushort_t* Kb    = (ushort_t*)(ws + 8 * MB);
    ushort_t* Vt    = (ushort_t*)(ws + 10 * MB);             // bf16 [bh][d][c]
    ushort_t* Aoutb = (ushort_t*)(ws + 12 * MB);             // bf16 [b*512+r][512]
    float* logitsBuf = (float*)(ws + 16 * MB);               // fp32 [bh][r][c] 33.6 MB

    convert_all<<<3072, 256, 0, stream>>>(row_emb, col_emb, Wq, Wk, Wv, Wout, convDst);

    gemm_qkv<<<dim3(32, 8, 3), 256, 0, stream>>>(rowb, colb, Wqb, Wkb, Wvb, Qb, Kb, Vt);

    dot_mlp_v5<<<dim3(16, 16, 4), 512, 0, stream>>>(Qb, Kb, cost, Wmix1, Wmix2, logitsBuf);

    softmax_pv<<<dim3(32, 32), 256, 0, stream>>>(logitsBuf, mask, Vt, Aoutb);

    gemm_out<<<dim3(32, 8), 256, 0, stream>>>(Aoutb, Woutb, out);
}